// Round 7
// baseline (239.070 us; speedup 1.0000x reference)
//
#include <hip/hip_runtime.h>
#include <hip/hip_bf16.h>

#define IN_SIZE 4096
#define OUT_SIZE 4096
#define BATCH 256
#define NNZ ((IN_SIZE * OUT_SIZE) / 2)   // 8388608

// Binning: 1024 buckets, bucket b = Wt rows [4b, 4b+4)  (Wt = W^T [out][in])
#define NB    1024
#define BBIN  1024             // binning blocks
#define BTHR  512              // threads per binning block
#define EPB   (NNZ / BBIN)     // 8192 elements per binning block
#define CHUNK 4096
#define NCH   (EPB / CHUNK)    // 2
#define REP    8               // counter replicas (blk & 7)
#define SUBCAP 1536            // per-replica sub-region (mean 1024, +16 sigma)
#define CAP    (REP * SUBCAP)  // 12288 slots per bucket
#define SPLITK 4

// GEMM tile
#define BM 64
#define BN 64
#define BK 64
#define LDA 72                 // padded LDS row stride (shorts): conflict-free

typedef float f32x4 __attribute__((ext_vector_type(4)));
typedef short s16x8 __attribute__((ext_vector_type(8)));

// ---- workspace layout (bytes) ----
static const size_t OFF_WTBF = 0;                               // Wt bf16: 32 MB
static const size_t OFF_PART = (size_t)32 << 20;                // 4 partials * 4 MB = 16 MB
static const size_t OFF_BIN  = (size_t)48 << 20;                // binned: 1024*12288*4 = 48 MB
static const size_t OFF_CNT  = (size_t)96 << 20;                // counters: 8*1024*4 = 32 KB
static const size_t WS_NEED  = OFF_CNT + (size_t)REP * NB * 4;  // ~96 MB

__device__ __forceinline__ short bfbits(float f) {
    __hip_bfloat16 h = __float2bfloat16(f);
    return __builtin_bit_cast(short, h);
}
__device__ __forceinline__ s16x8 pack8(f32x4 lo, f32x4 hi) {
    s16x8 r;
    r[0] = bfbits(lo[0]); r[1] = bfbits(lo[1]); r[2] = bfbits(lo[2]); r[3] = bfbits(lo[3]);
    r[4] = bfbits(hi[0]); r[5] = bfbits(hi[1]); r[6] = bfbits(hi[2]); r[7] = bfbits(hi[3]);
    return r;
}
// packed binned element: bits[29:14] = bf16(val) bits, bits[13:0] = pidx
__device__ __forceinline__ unsigned packel(int r, int c, float v) {
    return ((unsigned)(unsigned short)bfbits(v) << 14) |
           (unsigned)((c & 3) * IN_SIZE + r);
}
__device__ __forceinline__ float unpackv(unsigned p) {
    return __uint_as_float((p >> 14) << 16);
}

// Exclusive scan of 1024 u32 in LDS h -> out. 512 threads (2 vals/thread).
// Trailing __syncthreads() included.
__device__ __forceinline__ void scan1024(const unsigned* h, unsigned* out,
                                         unsigned* wsum, int t) {
    const int lane = t & 63, wid = t >> 6;   // 8 waves
    const unsigned a0 = h[2 * t], a1 = h[2 * t + 1];
    const unsigned s = a0 + a1;
    unsigned inc = s;
#pragma unroll
    for (int d = 1; d < 64; d <<= 1) {
        const unsigned n = __shfl_up(inc, d);
        if (lane >= d) inc += n;
    }
    if (lane == 63) wsum[wid] = inc;
    __syncthreads();
    unsigned wpre = 0;
#pragma unroll
    for (int i = 0; i < 8; ++i)
        if (i < wid) wpre += wsum[i];
    const unsigned ex = wpre + inc - s;
    out[2 * t]     = ex;
    out[2 * t + 1] = ex + a0;
    __syncthreads();
}

// ---------------------------------------------------------------------------
// K1: fused binning: LDS hist + scan + global atomic reserve + LDS reorder.
// 512 threads. cnt layout: cnt[rep][b]; region: b*CAP + rep*SUBCAP + off.
// ---------------------------------------------------------------------------
__global__ __launch_bounds__(BTHR) void k_bin(const int4* __restrict__ idx4,
                                              const float2* __restrict__ val2,
                                              unsigned* __restrict__ cnt,
                                              unsigned* __restrict__ binned) {
    __shared__ unsigned hist[NB], start[NB], curb[NB], wsum[8];
    __shared__ uint2 st[CHUNK];        // .x = global dst, .y = packed
    const int t = threadIdx.x, blk = blockIdx.x;
    const int rep = blk & (REP - 1);

    for (int ch = 0; ch < NCH; ++ch) {
        hist[2 * t] = 0; hist[2 * t + 1] = 0;
        __syncthreads();
        const int pbase = (blk * EPB + ch * CHUNK) / 2;
        unsigned eb[8], er[8], epk[8];
#pragma unroll
        for (int j = 0; j < 4; ++j) {
            const int4 e   = idx4[pbase + t + BTHR * j];
            const float2 v = val2[pbase + t + BTHR * j];
            eb[2 * j]      = ((unsigned)e.y) >> 2;
            epk[2 * j]     = packel(e.x, e.y, v.x);
            er[2 * j]      = atomicAdd(&hist[eb[2 * j]], 1u);
            eb[2 * j + 1]  = ((unsigned)e.w) >> 2;
            epk[2 * j + 1] = packel(e.z, e.w, v.y);
            er[2 * j + 1]  = atomicAdd(&hist[eb[2 * j + 1]], 1u);
        }
        __syncthreads();
        scan1024(hist, start, wsum, t);   // trailing barrier inside
        // reserve space for this chunk (thread t owns buckets 2t, 2t+1)
        {
            const unsigned h0 = hist[2 * t], h1 = hist[2 * t + 1];
            const unsigned r0 = h0 ? atomicAdd(&cnt[rep * NB + 2 * t], h0) : 0u;
            const unsigned r1 = h1 ? atomicAdd(&cnt[rep * NB + 2 * t + 1], h1) : 0u;
            curb[2 * t]     = (unsigned)(2 * t) * CAP + rep * SUBCAP + r0;
            curb[2 * t + 1] = (unsigned)(2 * t + 1) * CAP + rep * SUBCAP + r1;
        }
        __syncthreads();
#pragma unroll
        for (int j = 0; j < 8; ++j) {
            const unsigned lp = start[eb[j]] + er[j];
            st[lp] = make_uint2(curb[eb[j]] + er[j], epk[j]);
        }
        __syncthreads();
#pragma unroll
        for (int j = 0; j < 8; ++j) {
            const uint2 s = st[t + BTHR * j];
            binned[s.x] = s.y;
        }
        __syncthreads();
    }
}

// ---------------------------------------------------------------------------
// K2: per-bucket LDS accumulate -> Wt bf16 rows [4b, 4b+4). 1024 threads,
// 64 KB LDS (2 blocks/CU). 8 replica loads issued in parallel, then atomics.
// ---------------------------------------------------------------------------
__global__ __launch_bounds__(1024) void k_accum(const unsigned* __restrict__ binned,
                                                const unsigned* __restrict__ cnt,
                                                s16x8* __restrict__ Wtb8) {
    __shared__ float acc[4 * IN_SIZE];   // 64 KB
    const int t = threadIdx.x, b = blockIdx.x;
    f32x4* a4 = reinterpret_cast<f32x4*>(acc);
#pragma unroll
    for (int j = 0; j < (4 * IN_SIZE / 4) / 1024; ++j)   // 4
        a4[t + 1024 * j] = (f32x4){0.f, 0.f, 0.f, 0.f};
    __syncthreads();
    const unsigned base = (unsigned)b * CAP;
    unsigned n[REP];
#pragma unroll
    for (int r = 0; r < REP; ++r) {
        const unsigned c = cnt[r * NB + b];
        n[r] = c < SUBCAP ? c : SUBCAP;
    }
    // pass 1: element t of each replica region (8 loads in flight)
    unsigned p[REP]; bool v[REP];
#pragma unroll
    for (int r = 0; r < REP; ++r) {
        v[r] = (unsigned)t < n[r];
        p[r] = v[r] ? binned[base + r * SUBCAP + t] : 0u;
    }
#pragma unroll
    for (int r = 0; r < REP; ++r)
        if (v[r]) atomicAdd(&acc[p[r] & 16383u], unpackv(p[r]));
    // pass 2: element 1024+t (SUBCAP=1536 < 2048 so this covers everything)
#pragma unroll
    for (int r = 0; r < REP; ++r) {
        v[r] = (unsigned)(1024 + t) < n[r];
        p[r] = v[r] ? binned[base + r * SUBCAP + 1024 + t] : 0u;
    }
#pragma unroll
    for (int r = 0; r < REP; ++r)
        if (v[r]) atomicAdd(&acc[p[r] & 16383u], unpackv(p[r]));
    __syncthreads();
    s16x8* dst = Wtb8 + (size_t)b * (4 * IN_SIZE / 8);   // 2048 units
#pragma unroll
    for (int j = 0; j < (4 * IN_SIZE / 8) / 1024; ++j) { // 2
        const int i8 = t + 1024 * j;
        dst[i8] = pack8(a4[2 * i8], a4[2 * i8 + 1]);
    }
}

// ---------------------------------------------------------------------------
// K3: LDS-staged bf16 MFMA GEMM with fused X fp32->bf16 conversion.
// 64x64 tile, BK=64, 4 waves (each 32x32), split-K=4, LDA=72 conflict-free.
// Fragment maps verified rounds 2-6.
// ---------------------------------------------------------------------------
__global__ __launch_bounds__(256) void k_gemm(const float* __restrict__ X,
                                              const short* __restrict__ B,
                                              float* __restrict__ part) {
    __shared__ short As[BM * LDA];   // 18 KB
    __shared__ short Bs[BN * LDA];   // 18 KB
    const int t  = threadIdx.x;
    const int l  = t & 63;
    const int w  = t >> 6;
    const int wm = (w >> 1) * 32, wn = (w & 1) * 32;
    const int lr = l & 15, kg = (l >> 4) * 8;
    const int bn = blockIdx.x * BN, bm = blockIdx.y * BM;
    const size_t kb = (size_t)blockIdx.z * (IN_SIZE / SPLITK);

    const int r0s = t >> 3;            // rows 0..31 (phase 0)
    const int r1s = r0s + 32;          // rows 32..63 (phase 1)
    const int c0  = (t & 7) * 8;       // element offset within row
    const float* gA0 = X + (size_t)(bm + r0s) * IN_SIZE + kb + c0;
    const float* gA1 = X + (size_t)(bm + r1s) * IN_SIZE + kb + c0;
    const short* gB0 = B + (size_t)(bn + r0s) * IN_SIZE + kb + c0;
    const short* gB1 = B + (size_t)(bn + r1s) * IN_SIZE + kb + c0;

    f32x4 acc[2][2] = {};
    f32x4 a0lo = *reinterpret_cast<const f32x4*>(gA0);
    f32x4 a0hi = *reinterpret_cast<const f32x4*>(gA0 + 4);
    f32x4 a1lo = *reinterpret_cast<const f32x4*>(gA1);
    f32x4 a1hi = *reinterpret_cast<const f32x4*>(gA1 + 4);
    s16x8 rb0  = *reinterpret_cast<const s16x8*>(gB0);
    s16x8 rb1  = *reinterpret_cast<const s16x8*>(gB1);

    const int NIT = (IN_SIZE / SPLITK) / BK;   // 16
#pragma unroll 1
    for (int it = 0; it < NIT; ++it) {
        __syncthreads();   // previous iter's ds_reads complete
        *reinterpret_cast<s16x8*>(&As[r0s * LDA + c0]) = pack8(a0lo, a0hi);
        *reinterpret_cast<s16x8*>(&As[r1s * LDA + c0]) = pack8(a1lo, a1hi);
        *reinterpret_cast<s16x8*>(&Bs[r0s * LDA + c0]) = rb0;
        *reinterpret_cast<s16x8*>(&Bs[r1s * LDA + c0]) = rb1;
        __syncthreads();   // tile visible
        if (it + 1 < NIT) {
            const int o = (it + 1) * BK;
            a0lo = *reinterpret_cast<const f32x4*>(gA0 + o);
            a0hi = *reinterpret_cast<const f32x4*>(gA0 + o + 4);
            a1lo = *reinterpret_cast<const f32x4*>(gA1 + o);
            a1hi = *reinterpret_cast<const f32x4*>(gA1 + o + 4);
            rb0  = *reinterpret_cast<const s16x8*>(gB0 + o);
            rb1  = *reinterpret_cast<const s16x8*>(gB1 + o);
        }
        s16x8 af[2][2], bf[2][2];
#pragma unroll
        for (int kk = 0; kk < 2; ++kk) {
#pragma unroll
            for (int mi = 0; mi < 2; ++mi)
                af[kk][mi] = *reinterpret_cast<const s16x8*>(
                    &As[(wm + mi * 16 + lr) * LDA + kk * 32 + kg]);
#pragma unroll
            for (int ni = 0; ni < 2; ++ni)
                bf[kk][ni] = *reinterpret_cast<const s16x8*>(
                    &Bs[(wn + ni * 16 + lr) * LDA + kk * 32 + kg]);
        }
#pragma unroll
        for (int kk = 0; kk < 2; ++kk)
#pragma unroll
            for (int mi = 0; mi < 2; ++mi)
#pragma unroll
                for (int ni = 0; ni < 2; ++ni)
                    acc[mi][ni] = __builtin_amdgcn_mfma_f32_16x16x32_bf16(
                        af[kk][mi], bf[kk][ni], acc[mi][ni], 0, 0, 0);
    }

    float* P = part + (size_t)blockIdx.z * (BATCH * OUT_SIZE);
#pragma unroll
    for (int mi = 0; mi < 2; ++mi)
#pragma unroll
        for (int ni = 0; ni < 2; ++ni) {
            const int col = bn + wn + ni * 16 + lr;
            const int r0 = bm + wm + mi * 16 + ((l >> 4) << 2);
#pragma unroll
            for (int rr = 0; rr < 4; ++rr)
                P[(size_t)(r0 + rr) * OUT_SIZE + col] = acc[mi][ni][rr];
        }
}

// ---------------------------------------------------------------------------
// K4: Z = relu(sum of 4 partials + bias)
// ---------------------------------------------------------------------------
__global__ __launch_bounds__(256) void k_reduce(const float* __restrict__ part,
                                                const float* __restrict__ bias,
                                                float* __restrict__ Z) {
    const int i4 = blockIdx.x * 256 + threadIdx.x;
    f32x4 s = reinterpret_cast<const f32x4*>(part)[i4];
#pragma unroll
    for (int r = 1; r < SPLITK; ++r) {
        const f32x4 p = reinterpret_cast<const f32x4*>(part + (size_t)r * BATCH * OUT_SIZE)[i4];
#pragma unroll
        for (int k = 0; k < 4; ++k) s[k] += p[k];
    }
    const f32x4 bv = reinterpret_cast<const f32x4*>(bias)[i4 & (OUT_SIZE / 4 - 1)];
    f32x4 o;
#pragma unroll
    for (int k = 0; k < 4; ++k) o[k] = fmaxf(s[k] + bv[k], 0.f);
    reinterpret_cast<f32x4*>(Z)[i4] = o;
}

// ===========================================================================
// Fallback path (round-2, known-correct) if workspace is too small
// ===========================================================================
#define SC_BLOCKS 1024
__global__ __launch_bounds__(256) void scatter_t(const int2* __restrict__ idx2,
                                                 const float* __restrict__ val,
                                                 float* __restrict__ Wt) {
    const int stride = SC_BLOCKS * 256;
    int i = blockIdx.x * 256 + threadIdx.x;
#pragma unroll 1
    for (int iter = 0; iter < NNZ / (4 * SC_BLOCKS * 256); ++iter) {
        const int2 e0 = idx2[i];
        const int2 e1 = idx2[i + stride];
        const int2 e2 = idx2[i + 2 * stride];
        const int2 e3 = idx2[i + 3 * stride];
        const float v0 = val[i], v1 = val[i + stride], v2 = val[i + 2 * stride], v3 = val[i + 3 * stride];
        atomicAdd(&Wt[e0.y * IN_SIZE + e0.x], v0);
        atomicAdd(&Wt[e1.y * IN_SIZE + e1.x], v1);
        atomicAdd(&Wt[e2.y * IN_SIZE + e2.x], v2);
        atomicAdd(&Wt[e3.y * IN_SIZE + e3.x], v3);
        i += 4 * stride;
    }
}

__global__ __launch_bounds__(256) void gemm_mfma(const float* __restrict__ X,
                                                 const float* __restrict__ Wt,
                                                 const float* __restrict__ bias,
                                                 float* __restrict__ Z) {
    const int l = threadIdx.x & 63, w = threadIdx.x >> 6;
    const int bm = blockIdx.y * 128, bn = blockIdx.x * 32;
    const int lr = l & 15, kg = (l >> 4) * 8;
    const float* pA[2];
    const float* pB[2];
#pragma unroll
    for (int mi = 0; mi < 2; ++mi) pA[mi] = X + (bm + w * 32 + mi * 16 + lr) * IN_SIZE + kg;
#pragma unroll
    for (int ni = 0; ni < 2; ++ni) pB[ni] = Wt + (bn + ni * 16 + lr) * IN_SIZE + kg;
    f32x4 acc[2][2] = {};
#pragma unroll 2
    for (int k0 = 0; k0 < IN_SIZE; k0 += 32) {
        s16x8 a[2], b[2];
#pragma unroll
        for (int mi = 0; mi < 2; ++mi) {
            const f32x4 lo = *reinterpret_cast<const f32x4*>(pA[mi]);
            const f32x4 hi = *reinterpret_cast<const f32x4*>(pA[mi] + 4);
            a[mi] = pack8(lo, hi); pA[mi] += 32;
        }
#pragma unroll
        for (int ni = 0; ni < 2; ++ni) {
            const f32x4 lo = *reinterpret_cast<const f32x4*>(pB[ni]);
            const f32x4 hi = *reinterpret_cast<const f32x4*>(pB[ni] + 4);
            b[ni] = pack8(lo, hi); pB[ni] += 32;
        }
#pragma unroll
        for (int mi = 0; mi < 2; ++mi)
#pragma unroll
            for (int ni = 0; ni < 2; ++ni)
                acc[mi][ni] = __builtin_amdgcn_mfma_f32_16x16x32_bf16(a[mi], b[ni], acc[mi][ni], 0, 0, 0);
    }
#pragma unroll
    for (int mi = 0; mi < 2; ++mi)
#pragma unroll
        for (int ni = 0; ni < 2; ++ni) {
            const int col = bn + ni * 16 + lr;
            const float bv = bias[col];
            const int r0 = bm + w * 32 + mi * 16 + ((l >> 4) << 2);
#pragma unroll
            for (int rr = 0; rr < 4; ++rr)
                Z[(r0 + rr) * OUT_SIZE + col] = fmaxf(acc[mi][ni][rr] + bv, 0.f);
        }
}

extern "C" void kernel_launch(void* const* d_in, const int* in_sizes, int n_in,
                              void* d_out, int out_size, void* d_ws, size_t ws_size,
                              hipStream_t stream) {
    const float* X    = (const float*)d_in[0];
    const int*   idx  = (const int*)d_in[1];
    const float* val  = (const float*)d_in[2];
    const float* bias = (const float*)d_in[3];
    float* Z = (float*)d_out;
    char*  ws = (char*)d_ws;

    if (ws_size >= WS_NEED) {
        short*    Wtb    = (short*)(ws + OFF_WTBF);
        float*    part   = (float*)(ws + OFF_PART);
        unsigned* binned = (unsigned*)(ws + OFF_BIN);
        unsigned* cnt    = (unsigned*)(ws + OFF_CNT);

        hipMemsetAsync(cnt, 0, (size_t)REP * NB * 4, stream);
        k_bin<<<BBIN, BTHR, 0, stream>>>((const int4*)idx, (const float2*)val, cnt, binned);
        k_accum<<<NB, 1024, 0, stream>>>(binned, cnt, (s16x8*)Wtb);
        dim3 gg(OUT_SIZE / BN, BATCH / BM, SPLITK);
        k_gemm<<<gg, 256, 0, stream>>>(X, Wtb, part);
        k_reduce<<<(BATCH * OUT_SIZE) / (256 * 4), 256, 0, stream>>>(part, bias, Z);
    } else {
        float* Wt = (float*)d_ws;
        hipMemsetAsync(Wt, 0, (size_t)IN_SIZE * OUT_SIZE * sizeof(float), stream);
        scatter_t<<<SC_BLOCKS, 256, 0, stream>>>((const int2*)idx, val, Wt);
        dim3 grid(OUT_SIZE / 32, BATCH / 128);
        gemm_mfma<<<grid, 256, 0, stream>>>(X, Wt, bias, Z);
    }
}